// Round 3
// baseline (295.118 us; speedup 1.0000x reference)
//
#include <hip/hip_runtime.h>
#include <stdint.h>

// Problem constants
#define Bsz 4096
#define Tn  64      // scan length (char_seq[:, :-1])
#define T1n 65
#define Hn  64
#define Pn  50
#define Vn  32

typedef __attribute__((ext_vector_type(8))) short short8;
typedef __attribute__((ext_vector_type(4))) unsigned short bf16x4;
typedef __attribute__((ext_vector_type(4))) float floatx4;

__device__ __forceinline__ float bf2f(unsigned short u) {
  union { unsigned int i; float f; } x; x.i = ((unsigned int)u) << 16; return x.f;
}
__device__ __forceinline__ unsigned short f2bf(float f) {
  union { float f; unsigned int i; } x; x.f = f;
  return (unsigned short)((x.i + 0x7FFFu + ((x.i >> 16) & 1u)) >> 16);
}
__device__ __forceinline__ float fast_sigmoid(float x) {
  return __builtin_amdgcn_rcpf(1.f + __expf(-x));
}
__device__ __forceinline__ float fast_tanh(float x) {
  return 1.f - 2.f * __builtin_amdgcn_rcpf(1.f + __expf(2.f * x));
}

// B-operand fragment for mfma_f32_16x16x32_bf16 from row-major (K x ncols) fp32 weights.
__device__ __forceinline__ short8 load_bfrag(const float* __restrict__ W, int ncols, int col, int kbase) {
  short8 f;
#pragma unroll
  for (int j = 0; j < 8; ++j) f[j] = (short)f2bf(W[(long)(kbase + j) * ncols + col]);
  return f;
}

// R16 (= R15 + typedef fix): barrier-free single-wave scan. One wave owns all
// 16 batch rows of the block; gates are 4 N-tiles x 2 K-chunks of
// mfma_16x16x32 per gate (24 MFMA/step, zero M-waste). The rh and h
// transposes (the only cross-lane exchanges) are intra-wave LDS round-trips
// ordered by lgkmcnt -- NO s_barrier in the 64-step loop. Proj of h_{t-1}
// reuses the same A-fragments (lag 1); softmax + nll finish in-register per
// 16-lane group. Prologue (f32-exact tbl/ph tables, identical numerics to
// R13) runs on 4 waves; waves 1-3 exit.
__launch_bounds__(256, 1)
__global__ void gru_kernel(const float* __restrict__ phon,
                           const int* __restrict__ cs,
                           const float* __restrict__ emb,
                           const float* __restrict__ Wrx, const float* __restrict__ brx,
                           const float* __restrict__ Wrh, const float* __restrict__ brh,
                           const float* __restrict__ Wzx, const float* __restrict__ bzx,
                           const float* __restrict__ Wzh, const float* __restrict__ bzh,
                           const float* __restrict__ Whx, const float* __restrict__ bhx,
                           const float* __restrict__ Whh, const float* __restrict__ bhh,
                           const float* __restrict__ Wpj, const float* __restrict__ bpj_g,
                           float* __restrict__ ws,
                           float* __restrict__ outp) {
  // tblT[g][v][c16][n] = bf16( emb[v] @ W_gx[:64, col=16n+c16] + b_gx + b_gh ),
  // v-stride 68 shorts (136B) to spread banks across the 4 q-group codes.
  __shared__ __align__(16) unsigned short tblT[3 * 32 * 68];   // 13056 B
  // ph_s[g][c16][n*4+q][reg] = phon[row=q*4+reg] @ W_gx[64:, col=16n+c16]
  __shared__ __align__(16) float ph_s[3 * 16 * 68];            // 13056 B
  __shared__ __align__(16) unsigned short hT[16 * 72];         // bf16 h  [row][col]
  __shared__ __align__(16) unsigned short rhT[16 * 72];        // bf16 r*h[row][col]
  __shared__ unsigned int code4_s[(T1n + 1) * 4];              // packed codes [t][q]
  __shared__ int det_s[1];

  const int tid = threadIdx.x;
  const int b0 = blockIdx.x * 16;
  const int W8 = tid >> 6, lane = tid & 63, q = lane >> 4, c16 = lane & 15;
  const floatx4 zf = {0.f, 0.f, 0.f, 0.f};

  // --- int32-vs-int64 detection for char_seq ---
  if (tid == 0) det_s[0] = 0;
  __syncthreads();
  if (tid < 128 && cs[2 * tid + 1] != 0) atomicOr(&det_s[0], 1);
  __syncthreads();
  const bool is64 = (det_s[0] == 0);

  // --- wave 0: t-invariant register B-fragments (global loads, overlap prologue) ---
  short8 Br[4][2], Bz[4][2], Bh4[4][2], Bp[2][2];
  float bpj0 = 0.f, bpj1 = 0.f;
  if (W8 == 0) {
#pragma unroll
    for (int n = 0; n < 4; ++n)
#pragma unroll
      for (int kc = 0; kc < 2; ++kc) {
        Br[n][kc]  = load_bfrag(Wrh, Hn, n * 16 + c16, kc * 32 + q * 8);
        Bz[n][kc]  = load_bfrag(Wzh, Hn, n * 16 + c16, kc * 32 + q * 8);
        Bh4[n][kc] = load_bfrag(Whh, Hn, n * 16 + c16, kc * 32 + q * 8);
      }
#pragma unroll
    for (int n = 0; n < 2; ++n)
#pragma unroll
      for (int kc = 0; kc < 2; ++kc)
        Bp[n][kc] = load_bfrag(Wpj, Vn, n * 16 + c16, kc * 32 + q * 8);
    bpj0 = bpj_g[c16];
    bpj1 = bpj_g[16 + c16];
  }

  // --- codes staging (all 4 waves) ---
  for (int i = tid; i < T1n * 4; i += 256) {
    int t = i >> 2, qq = i & 3;
    unsigned int pk = 0;
#pragma unroll
    for (int r = 0; r < 4; ++r) {
      long idx = (long)(b0 + qq * 4 + r) * T1n + t;
      int c = is64 ? cs[2 * idx] : cs[idx];
      pk |= ((unsigned int)(c & 255)) << (8 * r);
    }
    code4_s[i] = pk;
  }

  // --- TBL (all 4 waves, f32 FMA -- numerics identical to R13) ---
  for (int g = 0; g < 3; ++g) {
    const float* Wg = (g == 0) ? Wrx : (g == 1) ? Wzx : Whx;
    const float* bx = (g == 0) ? brx : (g == 1) ? bzx : bhx;
    const float* bh = (g == 0) ? brh : (g == 1) ? bzh : bhh;
    float acc[8] = {0.f, 0.f, 0.f, 0.f, 0.f, 0.f, 0.f, 0.f};
    float bias = bx[lane] + bh[lane];
    for (int d = 0; d < Hn; ++d) {
      float wv = Wg[(long)d * Hn + lane];
#pragma unroll
      for (int k = 0; k < 8; ++k)
        acc[k] += emb[(long)(W8 + 4 * k) * Hn + d] * wv;
    }
#pragma unroll
    for (int k = 0; k < 8; ++k) {
      int v = W8 + 4 * k;
      tblT[g * 2176 + v * 68 + (lane & 15) * 4 + (lane >> 4)] = f2bf(acc[k] + bias);
    }
  }

  // --- PH (all 4 waves, f32): ph[g][row][col] for 3x16x64 values ---
  for (int i = tid; i < 3072; i += 256) {
    int g = i >> 10, rem = i & 1023, row = rem >> 6, col = rem & 63;
    const float* Wg = (g == 0) ? Wrx : (g == 1) ? Wzx : Whx;
    float acc = 0.f;
    for (int p = 0; p < Pn; ++p)
      acc += phon[(long)(b0 + row) * Pn + p] * Wg[(long)(Hn + p) * Hn + col];
    ph_s[g * 1088 + (col & 15) * 68 + ((col >> 4) * 4 + (row >> 2)) * 4 + (row & 3)] = acc;
  }

  __syncthreads();   // prologue done
  if (W8 != 0) return;   // waves 1-3 exit; wave 0 scans alone, barrier-free

  float h4[4][4] = {{0.f}};   // h state, C-layout: [n][reg] = h[row=q*4+reg][col=16n+c16]
  float hz[4][4];             // z-gate values, same layout
  float nll = 0.f, cnt = 0.f;
  const int us_w = q * 288 + c16;       // ushort idx: row=(q*4+reg) stride 72, col base c16
  const int us_r = c16 * 72 + q * 8;    // A-frag read: row c16, k chunk q*8

  for (int t = 0; t <= Tn; ++t) {
    const unsigned int pk = code4_s[t * 4 + q];

    // stage hT <- h (h_{t-1}; zeros at t=0). Intra-wave round-trip: the
    // compiler's lgkmcnt ordering replaces any barrier.
#pragma unroll
    for (int n = 0; n < 4; ++n)
#pragma unroll
      for (int reg = 0; reg < 4; ++reg)
        hT[us_w + reg * 72 + n * 16] = f2bf(h4[n][reg]);

    short8 a0 = *(const short8*)&hT[us_r];
    short8 a1 = *(const short8*)&hT[us_r + 32];

    // proj of h_{t-1} (output index p = t-1) reuses a0/a1
    floatx4 lp0 = zf, lp1 = zf;
    if (t > 0) {
      lp0 = __builtin_amdgcn_mfma_f32_16x16x32_bf16(a0, Bp[0][0], zf, 0, 0, 0);
      lp1 = __builtin_amdgcn_mfma_f32_16x16x32_bf16(a0, Bp[1][0], zf, 0, 0, 0);
      lp0 = __builtin_amdgcn_mfma_f32_16x16x32_bf16(a1, Bp[0][1], lp0, 0, 0, 0);
      lp1 = __builtin_amdgcn_mfma_f32_16x16x32_bf16(a1, Bp[1][1], lp1, 0, 0, 0);
    }

    bf16x4 tvr[4], tvz[4], tvh[4];
    if (t < Tn) {
      floatx4 accr[4], accz[4];
#pragma unroll
      for (int n = 0; n < 4; ++n) {
        accr[n] = __builtin_amdgcn_mfma_f32_16x16x32_bf16(a0, Br[n][0], zf, 0, 0, 0);
        accz[n] = __builtin_amdgcn_mfma_f32_16x16x32_bf16(a0, Bz[n][0], zf, 0, 0, 0);
      }
#pragma unroll
      for (int n = 0; n < 4; ++n) {
        accr[n] = __builtin_amdgcn_mfma_f32_16x16x32_bf16(a1, Br[n][1], accr[n], 0, 0, 0);
        accz[n] = __builtin_amdgcn_mfma_f32_16x16x32_bf16(a1, Bz[n][1], accz[n], 0, 0, 0);
      }
      // TBL fetch: one b64 per (gate, reg)
#pragma unroll
      for (int reg = 0; reg < 4; ++reg) {
        int cr = (pk >> (8 * reg)) & 255;
        int ti = cr * 68 + c16 * 4;
        tvr[reg] = *(const bf16x4*)&tblT[ti];
        tvz[reg] = *(const bf16x4*)&tblT[2176 + ti];
        tvh[reg] = *(const bf16x4*)&tblT[4352 + ti];
      }
      // r/z gates + rh staging
#pragma unroll
      for (int n = 0; n < 4; ++n) {
        floatx4 pr = *(const floatx4*)&ph_s[c16 * 68 + (n * 4 + q) * 4];
        floatx4 pz = *(const floatx4*)&ph_s[1088 + c16 * 68 + (n * 4 + q) * 4];
#pragma unroll
        for (int reg = 0; reg < 4; ++reg) {
          float xr = bf2f(tvr[reg][n]) + pr[reg] + accr[n][reg];
          float xz = bf2f(tvz[reg][n]) + pz[reg] + accz[n][reg];
          hz[n][reg] = fast_sigmoid(xz);
          rhT[us_w + reg * 72 + n * 16] = f2bf(fast_sigmoid(xr) * h4[n][reg]);
        }
      }
    }

    // proj epilogue: stores + softmax + nll (overlaps the rhT round-trip)
    if (t > 0) {
      const int p = t - 1;
#pragma unroll
      for (int reg = 0; reg < 4; ++reg) {
        float lg0 = lp0[reg] + bpj0;
        float lg1 = lp1[reg] + bpj1;
        long ad = ((long)(b0 + q * 4 + reg) * Tn + p) * Vn;
        outp[ad + c16]      = lg0;
        outp[ad + 16 + c16] = lg1;
        float s = __expf(lg0) + __expf(lg1);
        s += __shfl_xor(s, 1); s += __shfl_xor(s, 2);
        s += __shfl_xor(s, 4); s += __shfl_xor(s, 8);
        float lse = __logf(s);     // |logits| <= ~8, safe without max-sub
        int targ = (pk >> (8 * reg)) & 255;   // codes at t = p+1 = targets of p
        if (targ != 0) {
          if (c16 == targ)           { nll += lse - lg0; cnt += 1.f; }
          else if (c16 + 16 == targ) { nll += lse - lg1; cnt += 1.f; }
        }
      }
    }

    if (t < Tn) {
      // c gate + h update
      short8 p0 = *(const short8*)&rhT[us_r];
      short8 p1 = *(const short8*)&rhT[us_r + 32];
      floatx4 acch[4];
#pragma unroll
      for (int n = 0; n < 4; ++n)
        acch[n] = __builtin_amdgcn_mfma_f32_16x16x32_bf16(p0, Bh4[n][0], zf, 0, 0, 0);
#pragma unroll
      for (int n = 0; n < 4; ++n)
        acch[n] = __builtin_amdgcn_mfma_f32_16x16x32_bf16(p1, Bh4[n][1], acch[n], 0, 0, 0);
#pragma unroll
      for (int n = 0; n < 4; ++n) {
        floatx4 phh = *(const floatx4*)&ph_s[2176 + c16 * 68 + (n * 4 + q) * 4];
#pragma unroll
        for (int reg = 0; reg < 4; ++reg) {
          float xh = bf2f(tvh[reg][n]) + phh[reg] + acch[n][reg];
          float c = fast_tanh(xh);
          h4[n][reg] = fmaf(hz[n][reg], c - h4[n][reg], h4[n][reg]);
        }
      }
    }
  }

  // --- wave reduction -> per-block ws slot ---
#pragma unroll
  for (int off = 32; off >= 1; off >>= 1) {
    nll += __shfl_xor(nll, off);
    cnt += __shfl_xor(cnt, off);
  }
  if (lane == 0) {
    ws[2 * blockIdx.x] = nll;
    ws[2 * blockIdx.x + 1] = cnt;
  }
}

__global__ void loss_kernel(const float* __restrict__ ws, float* __restrict__ outp) {
  int lane = threadIdx.x;  // 64 threads
  float n = 0.f, c = 0.f;
  for (int i = lane; i < Bsz / 16; i += 64) { n += ws[2 * i]; c += ws[2 * i + 1]; }
#pragma unroll
  for (int off = 32; off >= 1; off >>= 1) {
    n += __shfl_xor(n, off);
    c += __shfl_xor(c, off);
  }
  if (lane == 0) outp[(size_t)Bsz * Tn * Vn] = n / fmaxf(c, 1.f);
}

extern "C" void kernel_launch(void* const* d_in, const int* in_sizes, int n_in,
                              void* d_out, int out_size, void* d_ws, size_t ws_size,
                              hipStream_t stream) {
  const float* phon = (const float*)d_in[0];
  const int*   cs   = (const int*)d_in[1];
  const float* emb  = (const float*)d_in[2];
  const float* Wrx  = (const float*)d_in[3];
  const float* brx  = (const float*)d_in[4];
  const float* Wrh  = (const float*)d_in[5];
  const float* brh  = (const float*)d_in[6];
  const float* Wzx  = (const float*)d_in[7];
  const float* bzx  = (const float*)d_in[8];
  const float* Wzh  = (const float*)d_in[9];
  const float* bzh  = (const float*)d_in[10];
  const float* Whx  = (const float*)d_in[11];
  const float* bhx  = (const float*)d_in[12];
  const float* Whh  = (const float*)d_in[13];
  const float* bhh  = (const float*)d_in[14];
  const float* Wpj  = (const float*)d_in[15];
  const float* bpj  = (const float*)d_in[16];
  float* ws = (float*)d_ws;

  hipLaunchKernelGGL(gru_kernel, dim3(Bsz / 16), dim3(256), 0, stream,
                     phon, cs, emb, Wrx, brx, Wrh, brh, Wzx, bzx, Wzh, bzh,
                     Whx, bhx, Whh, bhh, Wpj, bpj, ws, (float*)d_out);
  hipLaunchKernelGGL(loss_kernel, dim3(1), dim3(64), 0, stream, ws, (float*)d_out);
}

// Round 4
// 190.141 us; speedup vs baseline: 1.5521x; 1.5521x over previous
//
#include <hip/hip_runtime.h>
#include <stdint.h>

// Problem constants
#define Bsz 4096
#define Tn  64      // scan length (char_seq[:, :-1])
#define T1n 65
#define Hn  64
#define Pn  50
#define Vn  32

typedef __attribute__((ext_vector_type(8))) short short8;
typedef __attribute__((ext_vector_type(4))) unsigned short bf16x4;
typedef __attribute__((ext_vector_type(4))) float floatx4;

__device__ __forceinline__ float bf2f(unsigned short u) {
  union { unsigned int i; float f; } x; x.i = ((unsigned int)u) << 16; return x.f;
}
__device__ __forceinline__ unsigned short f2bf(float f) {
  union { float f; unsigned int i; } x; x.f = f;
  return (unsigned short)((x.i + 0x7FFFu + ((x.i >> 16) & 1u)) >> 16);
}
__device__ __forceinline__ float fast_sigmoid(float x) {
  return __builtin_amdgcn_rcpf(1.f + __expf(-x));
}
__device__ __forceinline__ float fast_tanh(float x) {
  return 1.f - 2.f * __builtin_amdgcn_rcpf(1.f + __expf(2.f * x));
}
// LDS-only barrier: global logit stores stay in flight (no vmcnt drain).
__device__ __forceinline__ void bar_lgkm() {
  asm volatile("s_waitcnt lgkmcnt(0)\n\ts_barrier" ::: "memory");
}

// B-operand fragment for mfma_f32_16x16x32_bf16 from row-major (K x ncols) fp32 weights.
__device__ __forceinline__ short8 load_bfrag(const float* __restrict__ W, int ncols, int col, int kbase) {
  short8 f;
#pragma unroll
  for (int j = 0; j < 8; ++j) f[j] = (short)f2bf(W[(long)(kbase + j) * ncols + col]);
  return f;
}

// R17 = R13 structure (8 waves, 2 barriers/step, known-good 85us) with the
// tail machinery deleted:
//  - proj waves 4/5 store logits straight to global in interval A, compute
//    per-row exp-sums via 4 shfl_xor chains in interval B (where they were
//    idle), and write sums + target-logit to a tiny LDS buffer;
//  - wave 6 finishes softmax/nll at lag 2 in interval A; wave 7 barriers only;
//  - no logit pages, no every-8-step tail burst, hist depth 8 -> 2;
//  - in-loop barriers are lgkmcnt-only (logit stores never drained in-loop);
//  - TBL packed: one b64 read yields r,z,h gate values (4 reads vs 12), and
//    is prefetched in interval B for step t+1 (shortens A's chain).
__launch_bounds__(512)
__global__ void gru_kernel(const float* __restrict__ phon,
                           const int* __restrict__ cs,
                           const float* __restrict__ emb,
                           const float* __restrict__ Wrx, const float* __restrict__ brx,
                           const float* __restrict__ Wrh, const float* __restrict__ brh,
                           const float* __restrict__ Wzx, const float* __restrict__ bzx,
                           const float* __restrict__ Wzh, const float* __restrict__ bzh,
                           const float* __restrict__ Whx, const float* __restrict__ bhx,
                           const float* __restrict__ Whh, const float* __restrict__ bhh,
                           const float* __restrict__ Wpj, const float* __restrict__ bpj_g,
                           float* __restrict__ ws,
                           float* __restrict__ outp) {
  __shared__ __align__(16) unsigned short tbl_s[32 * 66 * 4];  // [v][66 pad][g: r,z,h,-]
  __shared__ __align__(16) unsigned short hist_s[2 * 1152];    // bf16 h[t&1][m][72]
  __shared__ __align__(16) unsigned short rh_s[1152];          // bf16 r*h [m][72]
  __shared__ float sum_s[32];                                  // [half*16 + row]
  __shared__ float tl_s[16];                                   // target logit per row
  __shared__ unsigned int code4_s[(T1n + 1) * 4];              // packed codes [t][q]
  __shared__ int det_s[1];

  const int tid = threadIdx.x;
  const int b0 = blockIdx.x * 16;
  const int W8 = tid >> 6, lane = tid & 63, q = lane >> 4, c16 = lane & 15;
  const bool isScan = (W8 < 4);
  const int jcol = (W8 & 3) * 16 + c16;   // scan waves' col
  const floatx4 zf = {0.f, 0.f, 0.f, 0.f};

  // --- int32-vs-int64 detection for char_seq ---
  if (tid == 0) det_s[0] = 0;
  __syncthreads();
  if (tid < 128 && cs[2 * tid + 1] != 0) atomicOr(&det_s[0], 1);
  __syncthreads();
  const bool is64 = (det_s[0] == 0);

  // --- staging ---
  for (int i = tid; i < 1152; i += 512) hist_s[1152 + i] = 0;   // h0 slot (t=0 reads slot 1)
  for (int i = tid; i < T1n * 4; i += 512) {
    int t = i >> 2, qq = i & 3;
    unsigned int pk = 0;
#pragma unroll
    for (int r = 0; r < 4; ++r) {
      long idx = (long)(b0 + qq * 4 + r) * T1n + t;
      int c = is64 ? cs[2 * idx] : cs[idx];
      pk |= ((unsigned int)(c & 255)) << (8 * r);
    }
    code4_s[i] = pk;
  }

  // --- TBL: packed per (v, col): {r,z,h} = bf16( emb[v] @ W_gx[:64] + b_gx + b_gh ) ---
  for (int g = 0; g < 3; ++g) {
    const float* Wg = (g == 0) ? Wrx : (g == 1) ? Wzx : Whx;
    const float* bx = (g == 0) ? brx : (g == 1) ? bzx : bhx;
    const float* bh = (g == 0) ? brh : (g == 1) ? bzh : bhh;
    float acc[4] = {0.f, 0.f, 0.f, 0.f};
    float bias = bx[lane] + bh[lane];
    for (int d = 0; d < Hn; ++d) {
      float wv = Wg[(long)d * Hn + lane];
#pragma unroll
      for (int k = 0; k < 4; ++k)
        acc[k] += emb[(long)(W8 + 8 * k) * Hn + d] * wv;
    }
#pragma unroll
    for (int k = 0; k < 4; ++k) {
      int v = W8 + 8 * k;
      tbl_s[(v * 66 + lane) * 4 + g] = f2bf(acc[k] + bias);
    }
  }

  // --- PH per-lane (scan waves only): r, z, h gates ---
  float ph_r[4] = {0.f, 0.f, 0.f, 0.f};
  float ph_z[4] = {0.f, 0.f, 0.f, 0.f};
  float ph_h[4] = {0.f, 0.f, 0.f, 0.f};
  if (isScan) {
    for (int p = 0; p < Pn; ++p) {
      float wr = Wrx[(long)(Hn + p) * Hn + jcol];
      float wz = Wzx[(long)(Hn + p) * Hn + jcol];
      float wh = Whx[(long)(Hn + p) * Hn + jcol];
#pragma unroll
      for (int r = 0; r < 4; ++r) {
        float xv = phon[(long)(b0 + q * 4 + r) * Pn + p];
        ph_r[r] += xv * wr; ph_z[r] += xv * wz; ph_h[r] += xv * wh;
      }
    }
  }

  // --- B-fragments (register-resident, t-invariant) ---
  short8 zs = {0,0,0,0,0,0,0,0};
  short8 Br0 = zs, Br1 = zs, Bz0 = zs, Bz1 = zs, Bh0 = zs, Bh1 = zs;
  short8 Bp0 = zs, Bp1 = zs;
  float bpj = 0.f;
  const int vt = W8 - 4;   // proj half index (waves 4,5)
  if (isScan) {
    Br0 = load_bfrag(Wrh, Hn, jcol, q * 8);
    Br1 = load_bfrag(Wrh, Hn, jcol, 32 + q * 8);
    Bz0 = load_bfrag(Wzh, Hn, jcol, q * 8);
    Bz1 = load_bfrag(Wzh, Hn, jcol, 32 + q * 8);
    Bh0 = load_bfrag(Whh, Hn, jcol, q * 8);
    Bh1 = load_bfrag(Whh, Hn, jcol, 32 + q * 8);
  } else if (W8 < 6) {
    Bp0 = load_bfrag(Wpj, Vn, vt * 16 + c16, q * 8);
    Bp1 = load_bfrag(Wpj, Vn, vt * 16 + c16, 32 + q * 8);
    bpj = bpj_g[vt * 16 + c16];
  }

  float h[4] = {0.f, 0.f, 0.f, 0.f};
  float z4[4] = {0.f, 0.f, 0.f, 0.f};
  float nll = 0.f, cnt = 0.f;
  bf16x4 tv[4];              // scan: packed {r,z,h} TBL values, prefetched B -> A
  float eA[4], lgA[4];       // proj: exps + logits, A -> B
  bool tm[4] = {false, false, false, false};

  if (isScan) {
    unsigned int pk0 = code4_s[q];
#pragma unroll
    for (int reg = 0; reg < 4; ++reg) {
      int cr = (pk0 >> (8 * reg)) & 255;
      tv[reg] = *(const bf16x4*)&tbl_s[(cr * 66 + jcol) * 4];
    }
  }

  __syncthreads();   // prologue done

  for (int t = 0; t < Tn + 2; ++t) {
    // ===== interval A =====
    if (isScan) {
      if (t < Tn) {
        const unsigned short* hp = &hist_s[((t + 1) & 1) * 1152];
        short8 a0 = *(const short8*)&hp[c16 * 72 + q * 8];
        short8 a1 = *(const short8*)&hp[c16 * 72 + 32 + q * 8];
        floatx4 accr = __builtin_amdgcn_mfma_f32_16x16x32_bf16(a0, Br0, zf, 0, 0, 0);
        floatx4 accz = __builtin_amdgcn_mfma_f32_16x16x32_bf16(a0, Bz0, zf, 0, 0, 0);
        accr = __builtin_amdgcn_mfma_f32_16x16x32_bf16(a1, Br1, accr, 0, 0, 0);
        accz = __builtin_amdgcn_mfma_f32_16x16x32_bf16(a1, Bz1, accz, 0, 0, 0);
#pragma unroll
        for (int reg = 0; reg < 4; ++reg) {
          float xr = bf2f(tv[reg][0]) + ph_r[reg] + accr[reg];
          float xz = bf2f(tv[reg][1]) + ph_z[reg] + accz[reg];
          z4[reg] = fast_sigmoid(xz);
          rh_s[(q * 4 + reg) * 72 + jcol] = f2bf(fast_sigmoid(xr) * h[reg]);
        }
      }
    } else if (W8 < 6) {
      if (t >= 1 && t <= Tn) {       // proj h_{t-1} -> output index p = t-1
        const unsigned short* hp = &hist_s[((t + 1) & 1) * 1152];
        short8 a0 = *(const short8*)&hp[c16 * 72 + q * 8];
        short8 a1 = *(const short8*)&hp[c16 * 72 + 32 + q * 8];
        floatx4 l = __builtin_amdgcn_mfma_f32_16x16x32_bf16(a0, Bp0, zf, 0, 0, 0);
        l = __builtin_amdgcn_mfma_f32_16x16x32_bf16(a1, Bp1, l, 0, 0, 0);
        const int p = t - 1;
        unsigned int pkP = code4_s[t * 4 + q];   // codes at t = targets of p
#pragma unroll
        for (int reg = 0; reg < 4; ++reg) {
          float lg = l[reg] + bpj;
          lgA[reg] = lg;
          eA[reg] = __expf(lg);
          long ad = ((long)(b0 + q * 4 + reg) * Tn + p) * Vn + vt * 16 + c16;
          outp[ad] = lg;
          int targ = (pkP >> (8 * reg)) & 255;
          tm[reg] = (targ != 0) && (targ == vt * 16 + c16);
        }
      }
    } else if (W8 == 6) {
      if (t >= 2 && lane < 16) {     // finish softmax/nll for p = t-2
        unsigned int pk6 = code4_s[(t - 1) * 4 + (lane >> 2)];
        int targ = (pk6 >> (8 * (lane & 3))) & 255;
        if (targ != 0) {
          float s = sum_s[lane] + sum_s[16 + lane];
          nll += __logf(s) - tl_s[lane];   // |logits| <= ~8, safe without max-sub
          cnt += 1.f;
        }
      }
    }
    bar_lgkm();  // A

    // ===== interval B =====
    if (isScan) {
      if (t < Tn) {      // c-gate + h-update -> hist_s[t&1]
        short8 p0 = *(const short8*)&rh_s[c16 * 72 + q * 8];
        short8 p1 = *(const short8*)&rh_s[c16 * 72 + 32 + q * 8];
        floatx4 acc = __builtin_amdgcn_mfma_f32_16x16x32_bf16(p0, Bh0, zf, 0, 0, 0);
        acc = __builtin_amdgcn_mfma_f32_16x16x32_bf16(p1, Bh1, acc, 0, 0, 0);
        unsigned short* hw = &hist_s[(t & 1) * 1152];
#pragma unroll
        for (int reg = 0; reg < 4; ++reg) {
          float xh = bf2f(tv[reg][2]) + ph_h[reg] + acc[reg];
          float c = fast_tanh(xh);
          float hn = fmaf(z4[reg], c - h[reg], h[reg]);
          h[reg] = hn;
          hw[(q * 4 + reg) * 72 + jcol] = f2bf(hn);
        }
        // prefetch packed TBL values for step t+1
        unsigned int pkN = code4_s[(t + 1) * 4 + q];
#pragma unroll
        for (int reg = 0; reg < 4; ++reg) {
          int crN = (pkN >> (8 * reg)) & 255;
          tv[reg] = *(const bf16x4*)&tbl_s[(crN * 66 + jcol) * 4];
        }
      }
    } else if (W8 < 6) {
      if (t >= 1 && t <= Tn) {   // per-row exp-sums over this vocab half
#pragma unroll
        for (int reg = 0; reg < 4; ++reg) {
          float s = eA[reg];
          s += __shfl_xor(s, 1); s += __shfl_xor(s, 2);
          s += __shfl_xor(s, 4); s += __shfl_xor(s, 8);
          if (c16 == 0) sum_s[vt * 16 + q * 4 + reg] = s;
          if (tm[reg])  tl_s[q * 4 + reg] = lgA[reg];
        }
      }
    }
    bar_lgkm();  // B
  }

  // ===== wave 6: nll/cnt reduction -> per-block ws slot =====
  if (W8 == 6) {
#pragma unroll
    for (int off = 8; off >= 1; off >>= 1) {   // lanes 16-63 hold zeros
      nll += __shfl_xor(nll, off);
      cnt += __shfl_xor(cnt, off);
    }
    if (lane == 0) {
      ws[2 * blockIdx.x] = nll;
      ws[2 * blockIdx.x + 1] = cnt;
    }
  }
}

__global__ void loss_kernel(const float* __restrict__ ws, float* __restrict__ outp) {
  int lane = threadIdx.x;  // 64 threads
  float n = 0.f, c = 0.f;
  for (int i = lane; i < Bsz / 16; i += 64) { n += ws[2 * i]; c += ws[2 * i + 1]; }
#pragma unroll
  for (int off = 32; off >= 1; off >>= 1) {
    n += __shfl_xor(n, off);
    c += __shfl_xor(c, off);
  }
  if (lane == 0) outp[(size_t)Bsz * Tn * Vn] = n / fmaxf(c, 1.f);
}

extern "C" void kernel_launch(void* const* d_in, const int* in_sizes, int n_in,
                              void* d_out, int out_size, void* d_ws, size_t ws_size,
                              hipStream_t stream) {
  const float* phon = (const float*)d_in[0];
  const int*   cs   = (const int*)d_in[1];
  const float* emb  = (const float*)d_in[2];
  const float* Wrx  = (const float*)d_in[3];
  const float* brx  = (const float*)d_in[4];
  const float* Wrh  = (const float*)d_in[5];
  const float* brh  = (const float*)d_in[6];
  const float* Wzx  = (const float*)d_in[7];
  const float* bzx  = (const float*)d_in[8];
  const float* Wzh  = (const float*)d_in[9];
  const float* bzh  = (const float*)d_in[10];
  const float* Whx  = (const float*)d_in[11];
  const float* bhx  = (const float*)d_in[12];
  const float* Whh  = (const float*)d_in[13];
  const float* bhh  = (const float*)d_in[14];
  const float* Wpj  = (const float*)d_in[15];
  const float* bpj  = (const float*)d_in[16];
  float* ws = (float*)d_ws;

  hipLaunchKernelGGL(gru_kernel, dim3(Bsz / 16), dim3(512), 0, stream,
                     phon, cs, emb, Wrx, brx, Wrh, brh, Wzx, bzx, Wzh, bzh,
                     Whx, bhx, Whh, bhh, Wpj, bpj, ws, (float*)d_out);
  hipLaunchKernelGGL(loss_kernel, dim3(1), dim3(64), 0, stream, ws, (float*)d_out);
}

// Round 5
// 176.761 us; speedup vs baseline: 1.6696x; 1.0757x over previous
//
#include <hip/hip_runtime.h>
#include <stdint.h>

// Problem constants
#define Bsz 4096
#define Tn  64      // scan length (char_seq[:, :-1])
#define T1n 65
#define Hn  64
#define Pn  50
#define Vn  32

typedef __attribute__((ext_vector_type(8))) short short8;
typedef __attribute__((ext_vector_type(4))) unsigned short bf16x4;
typedef __attribute__((ext_vector_type(4))) float floatx4;

__device__ __forceinline__ float bf2f(unsigned short u) {
  union { unsigned int i; float f; } x; x.i = ((unsigned int)u) << 16; return x.f;
}
__device__ __forceinline__ unsigned short f2bf(float f) {
  union { float f; unsigned int i; } x; x.f = f;
  return (unsigned short)((x.i + 0x7FFFu + ((x.i >> 16) & 1u)) >> 16);
}
__device__ __forceinline__ unsigned int packbf(float a, float b) {
  return (unsigned int)f2bf(a) | ((unsigned int)f2bf(b) << 16);
}
__device__ __forceinline__ float fast_sigmoid(float x) {
  return __builtin_amdgcn_rcpf(1.f + __expf(-x));
}
__device__ __forceinline__ float fast_tanh(float x) {
  return 1.f - 2.f * __builtin_amdgcn_rcpf(1.f + __expf(2.f * x));
}
// LDS-only barrier: global logit stores stay in flight (no vmcnt drain).
__device__ __forceinline__ void bar_lgkm() {
  asm volatile("s_waitcnt lgkmcnt(0)\n\ts_barrier" ::: "memory");
}

// A/B-operand fragment for mfma_f32_16x16x32_bf16 from row-major (K x ncols)
// fp32 weights: f[j] = W[kbase+j][col].
__device__ __forceinline__ short8 load_bfrag(const float* __restrict__ W, int ncols, int col, int kbase) {
  short8 f;
#pragma unroll
  for (int j = 0; j < 8; ++j) f[j] = (short)f2bf(W[(long)(kbase + j) * ncols + col]);
  return f;
}

// R18: transposed dataflow. Gates computed as W^T @ h^T (units = M, batch = N=16,
// zero lane waste). Weights are register A-frags; gate wave w owns units
// [16w,16w+16). Per-lane state: batch = lane&15, units = 16w+4q+reg. The only
// cross-wave exchange is packed h^T / rh^T: 1 ds_write_b64 + 2 ds_read_b128
// per wave per interval (vs ~20 scalar LDS ops in R13). Proj waves 4,5 compute
// the two 16-vocab logit tiles (A: 2 MFMAs), store one dwordx4/lane and fold
// softmax partials into interval B; wave 6 finalizes nll at lag 2. No tail
// bursts, no logit pages. Numerics bit-identical to R13's value path.
__launch_bounds__(512)
__global__ void gru_kernel(const float* __restrict__ phon,
                           const int* __restrict__ cs,
                           const float* __restrict__ emb,
                           const float* __restrict__ Wrx, const float* __restrict__ brx,
                           const float* __restrict__ Wrh, const float* __restrict__ brh,
                           const float* __restrict__ Wzx, const float* __restrict__ bzx,
                           const float* __restrict__ Wzh, const float* __restrict__ bzh,
                           const float* __restrict__ Whx, const float* __restrict__ bhx,
                           const float* __restrict__ Whh, const float* __restrict__ bhh,
                           const float* __restrict__ Wpj, const float* __restrict__ bpj_g,
                           float* __restrict__ ws,
                           float* __restrict__ outp) {
  __shared__ __align__(16) unsigned short tbl_s[3 * 32 * 68];  // [g][code][unit(64,pad68)] bf16
  __shared__ __align__(16) unsigned int hp_s[16 * 36];         // h^T packed pairs [batch][pair(32,pad36)]
  __shared__ __align__(16) unsigned int rhp_s[16 * 36];        // rh^T packed pairs
  __shared__ unsigned char codes_s[66 * 16];                   // [pos][batch]
  __shared__ float sum_s[2 * 16];                              // exp-sums [vhalf][batch]
  __shared__ float tl_s[16];                                   // target logit [batch]
  __shared__ int det_s[1];

  const int tid = threadIdx.x;
  const int b0 = blockIdx.x * 16;
  const int W8 = tid >> 6, lane = tid & 63, q = lane >> 4, c16 = lane & 15;
  const floatx4 zf = {0.f, 0.f, 0.f, 0.f};

  // --- int32-vs-int64 detection for char_seq ---
  if (tid == 0) det_s[0] = 0;
  __syncthreads();
  if (tid < 128 && cs[2 * tid + 1] != 0) atomicOr(&det_s[0], 1);
  __syncthreads();
  const bool is64 = (det_s[0] == 0);

  // --- staging: h0 = 0, codes ---
  for (int i = tid; i < 16 * 36; i += 512) hp_s[i] = 0;
  for (int i = tid; i < 65 * 16; i += 512) {
    int t = i >> 4, b = i & 15;
    long idx = (long)(b0 + b) * T1n + t;
    int c = is64 ? cs[2 * idx] : cs[idx];
    codes_s[i] = (unsigned char)(c & 255);
  }

  // --- TBL (all 8 waves, f32 FMA): tbl[g][v][unit] = emb[v]@W_gx[:64,unit] + bx + bh ---
  for (int g = 0; g < 3; ++g) {
    const float* Wg = (g == 0) ? Wrx : (g == 1) ? Wzx : Whx;
    const float* bx = (g == 0) ? brx : (g == 1) ? bzx : bhx;
    const float* bh = (g == 0) ? brh : (g == 1) ? bzh : bhh;
    float acc[4] = {0.f, 0.f, 0.f, 0.f};
    float bias = bx[lane] + bh[lane];
    for (int d = 0; d < Hn; ++d) {
      float wv = Wg[(long)d * Hn + lane];
#pragma unroll
      for (int k = 0; k < 4; ++k)
        acc[k] += emb[(long)(W8 + 8 * k) * Hn + d] * wv;
    }
#pragma unroll
    for (int k = 0; k < 4; ++k)
      tbl_s[g * 2176 + (W8 + 8 * k) * 68 + lane] = f2bf(acc[k] + bias);
  }

  // --- roles ---
  const bool isGate = (W8 < 4);
  const bool isProj = (W8 == 4 || W8 == 5);
  const int w = W8 & 3;          // gate unit-tile
  const int m = W8 - 4;          // proj vocab-tile
  const int tb = 16 * w + 4 * q; // gate C-side unit base (units tb..tb+3)

  // --- t-invariant register fragments + per-lane PH ---
  short8 zs = {0,0,0,0,0,0,0,0};
  short8 Ar0 = zs, Ar1 = zs, Az0 = zs, Az1 = zs, Ah0 = zs, Ah1 = zs;
  short8 Ap0 = zs, Ap1 = zs;
  float ph_r[4] = {0,0,0,0}, ph_z[4] = {0,0,0,0}, ph_h[4] = {0,0,0,0};
  float bpjr[4] = {0,0,0,0};
  if (isGate) {
    // A-frag rows are units 16w + c16; k = 32kc + 8q + j
    Ar0 = load_bfrag(Wrh, Hn, 16 * w + c16, 8 * q);
    Ar1 = load_bfrag(Wrh, Hn, 16 * w + c16, 32 + 8 * q);
    Az0 = load_bfrag(Wzh, Hn, 16 * w + c16, 8 * q);
    Az1 = load_bfrag(Wzh, Hn, 16 * w + c16, 32 + 8 * q);
    Ah0 = load_bfrag(Whh, Hn, 16 * w + c16, 8 * q);
    Ah1 = load_bfrag(Whh, Hn, 16 * w + c16, 32 + 8 * q);
    // PH: ph_g[reg] = phon[b0+c16] @ W_gx[64:, unit tb+reg]  (f32, same order as R13)
    for (int p = 0; p < Pn; ++p) {
      float xv = phon[(long)(b0 + c16) * Pn + p];
      floatx4 wr = *(const floatx4*)&Wrx[(long)(Hn + p) * Hn + tb];
      floatx4 wz = *(const floatx4*)&Wzx[(long)(Hn + p) * Hn + tb];
      floatx4 wh = *(const floatx4*)&Whx[(long)(Hn + p) * Hn + tb];
#pragma unroll
      for (int reg = 0; reg < 4; ++reg) {
        ph_r[reg] += xv * wr[reg];
        ph_z[reg] += xv * wz[reg];
        ph_h[reg] += xv * wh[reg];
      }
    }
  } else if (isProj) {
    Ap0 = load_bfrag(Wpj, Vn, 16 * m + c16, 8 * q);
    Ap1 = load_bfrag(Wpj, Vn, 16 * m + c16, 32 + 8 * q);
#pragma unroll
    for (int reg = 0; reg < 4; ++reg) bpjr[reg] = bpj_g[16 * m + 4 * q + reg];
  }

  // LDS index helpers (u32 units). Row stride 36 keeps b128 reads 16B-aligned.
  const int hp_rd = c16 * 36 + 4 * q;            // chunk kc adds +16
  const int hp_wr = c16 * 36 + 8 * w + 2 * q;    // gate waves only

  float h4[4] = {0.f, 0.f, 0.f, 0.f};
  float z4[4] = {0.f, 0.f, 0.f, 0.f};
  float nll = 0.f, cnt = 0.f;
  int code = 0;
  floatx4 lacc = zf;

  __syncthreads();   // prologue done

  for (int t = 0; t <= Tn + 1; ++t) {
    // ===== interval A =====
    if (isGate) {
      if (t < Tn) {
        code = codes_s[t * 16 + c16];
        short8 hb0 = *(const short8*)&hp_s[hp_rd];
        short8 hb1 = *(const short8*)&hp_s[hp_rd + 16];
        floatx4 accr = __builtin_amdgcn_mfma_f32_16x16x32_bf16(Ar0, hb0, zf, 0, 0, 0);
        floatx4 accz = __builtin_amdgcn_mfma_f32_16x16x32_bf16(Az0, hb0, zf, 0, 0, 0);
        accr = __builtin_amdgcn_mfma_f32_16x16x32_bf16(Ar1, hb1, accr, 0, 0, 0);
        accz = __builtin_amdgcn_mfma_f32_16x16x32_bf16(Az1, hb1, accz, 0, 0, 0);
        bf16x4 tvr = *(const bf16x4*)&tbl_s[code * 68 + tb];
        bf16x4 tvz = *(const bf16x4*)&tbl_s[2176 + code * 68 + tb];
        float rh[4];
#pragma unroll
        for (int reg = 0; reg < 4; ++reg) {
          float xr = bf2f(tvr[reg]) + ph_r[reg] + accr[reg];
          float xz = bf2f(tvz[reg]) + ph_z[reg] + accz[reg];
          z4[reg] = fast_sigmoid(xz);
          rh[reg] = fast_sigmoid(xr) * h4[reg];
        }
        unsigned long long wv = (unsigned long long)packbf(rh[0], rh[1])
                              | ((unsigned long long)packbf(rh[2], rh[3]) << 32);
        *(unsigned long long*)&rhp_s[hp_wr] = wv;
      }
    } else if (isProj) {
      if (t >= 1 && t <= Tn) {     // proj h_{t-1} (hp_s still holds it)
        short8 hb0 = *(const short8*)&hp_s[hp_rd];
        short8 hb1 = *(const short8*)&hp_s[hp_rd + 16];
        lacc = __builtin_amdgcn_mfma_f32_16x16x32_bf16(Ap0, hb0, zf, 0, 0, 0);
        lacc = __builtin_amdgcn_mfma_f32_16x16x32_bf16(Ap1, hb1, lacc, 0, 0, 0);
      }
    } else if (W8 == 6) {
      if (t >= 2 && lane < 16) {   // finalize softmax/nll for p = t-2
        int targ = codes_s[(t - 1) * 16 + lane];
        if (targ != 0) {
          float s = sum_s[lane] + sum_s[16 + lane];
          nll += __logf(s) - tl_s[lane];   // |logits| <= ~8, safe without max-sub
          cnt += 1.f;
        }
      }
    }
    bar_lgkm();  // A

    // ===== interval B =====
    if (isGate) {
      if (t < Tn) {
        short8 p0 = *(const short8*)&rhp_s[hp_rd];
        short8 p1 = *(const short8*)&rhp_s[hp_rd + 16];
        floatx4 acch = __builtin_amdgcn_mfma_f32_16x16x32_bf16(Ah0, p0, zf, 0, 0, 0);
        acch = __builtin_amdgcn_mfma_f32_16x16x32_bf16(Ah1, p1, acch, 0, 0, 0);
        bf16x4 tvh = *(const bf16x4*)&tbl_s[4352 + code * 68 + tb];
#pragma unroll
        for (int reg = 0; reg < 4; ++reg) {
          float xh = bf2f(tvh[reg]) + ph_h[reg] + acch[reg];
          float c = fast_tanh(xh);
          h4[reg] = fmaf(z4[reg], c - h4[reg], h4[reg]);
        }
        unsigned long long wv = (unsigned long long)packbf(h4[0], h4[1])
                              | ((unsigned long long)packbf(h4[2], h4[3]) << 32);
        *(unsigned long long*)&hp_s[hp_wr] = wv;
      }
    } else if (isProj) {
      if (t >= 1 && t <= Tn) {
        const int p = t - 1;
        float lg[4]; float e = 0.f;
#pragma unroll
        for (int reg = 0; reg < 4; ++reg) {
          lg[reg] = lacc[reg] + bpjr[reg];
          e += __expf(lg[reg]);
        }
        e += __shfl_xor(e, 16);
        e += __shfl_xor(e, 32);
        if (q == 0) sum_s[m * 16 + c16] = e;
        int targ = codes_s[t * 16 + c16];     // target of p is code at position t
#pragma unroll
        for (int reg = 0; reg < 4; ++reg)
          if (targ != 0 && targ == 16 * m + 4 * q + reg) tl_s[c16] = lg[reg];
        floatx4 st = {lg[0], lg[1], lg[2], lg[3]};
        *(floatx4*)&outp[((long)(b0 + c16) * Tn + p) * Vn + 16 * m + 4 * q] = st;
      }
    }
    bar_lgkm();  // B
  }

  // ===== wave 6: nll/cnt reduction -> per-block ws slot =====
  if (W8 == 6) {
#pragma unroll
    for (int off = 8; off >= 1; off >>= 1) {   // lanes 16-63 hold zeros
      nll += __shfl_xor(nll, off);
      cnt += __shfl_xor(cnt, off);
    }
    if (lane == 0) {
      ws[2 * blockIdx.x] = nll;
      ws[2 * blockIdx.x + 1] = cnt;
    }
  }
}

__global__ void loss_kernel(const float* __restrict__ ws, float* __restrict__ outp) {
  int lane = threadIdx.x;  // 64 threads
  float n = 0.f, c = 0.f;
  for (int i = lane; i < Bsz / 16; i += 64) { n += ws[2 * i]; c += ws[2 * i + 1]; }
#pragma unroll
  for (int off = 32; off >= 1; off >>= 1) {
    n += __shfl_xor(n, off);
    c += __shfl_xor(c, off);
  }
  if (lane == 0) outp[(size_t)Bsz * Tn * Vn] = n / fmaxf(c, 1.f);
}

extern "C" void kernel_launch(void* const* d_in, const int* in_sizes, int n_in,
                              void* d_out, int out_size, void* d_ws, size_t ws_size,
                              hipStream_t stream) {
  const float* phon = (const float*)d_in[0];
  const int*   cs   = (const int*)d_in[1];
  const float* emb  = (const float*)d_in[2];
  const float* Wrx  = (const float*)d_in[3];
  const float* brx  = (const float*)d_in[4];
  const float* Wrh  = (const float*)d_in[5];
  const float* brh  = (const float*)d_in[6];
  const float* Wzx  = (const float*)d_in[7];
  const float* bzx  = (const float*)d_in[8];
  const float* Wzh  = (const float*)d_in[9];
  const float* bzh  = (const float*)d_in[10];
  const float* Whx  = (const float*)d_in[11];
  const float* bhx  = (const float*)d_in[12];
  const float* Whh  = (const float*)d_in[13];
  const float* bhh  = (const float*)d_in[14];
  const float* Wpj  = (const float*)d_in[15];
  const float* bpj  = (const float*)d_in[16];
  float* ws = (float*)d_ws;

  hipLaunchKernelGGL(gru_kernel, dim3(Bsz / 16), dim3(512), 0, stream,
                     phon, cs, emb, Wrx, brx, Wrh, brh, Wzx, bzx, Wzh, bzh,
                     Whx, bhx, Whh, bhh, Wpj, bpj, ws, (float*)d_out);
  hipLaunchKernelGGL(loss_kernel, dim3(1), dim3(64), 0, stream, ws, (float*)d_out);
}